// Round 15
// baseline (308.147 us; speedup 1.0000x reference)
//
#include <hip/hip_runtime.h>
#include <hip/hip_cooperative_groups.h>
#include <math.h>

namespace cg = cooperative_groups;

namespace {

typedef __attribute__((ext_vector_type(8))) short          bf16x8;
typedef __attribute__((ext_vector_type(8))) unsigned short u16x8;
typedef __attribute__((ext_vector_type(8))) _Float16       f16x8;
typedef __attribute__((ext_vector_type(4))) float          f32x4;

constexpr int B_  = 2;
constexpr int H_  = 96;
constexpr int W_  = 96;
constexpr int HW_ = H_ * W_;
constexpr int NC_ = 64;
constexpr int SC_ = 64;

__device__ inline unsigned short f2bf(float f) {
    union { float f; unsigned u; } v; v.f = f;
    unsigned r = v.u + 0x7FFFu + ((v.u >> 16) & 1u);
    return (unsigned short)(r >> 16);
}
__device__ inline float bf2f(unsigned short s) {
    union { unsigned u; float f; } v; v.u = ((unsigned)s) << 16; return v.f;
}
__device__ inline unsigned short f2hbits(float f) {
    union { _Float16 h; unsigned short u; } s; s.h = (_Float16)f; return s.u;
}
__device__ inline _Float16 hfrombits(unsigned short u) {
    union { _Float16 h; unsigned short u; } s; s.u = u; return s.h;
}
__device__ inline bf16x8 ld_frag(const unsigned short* p) {
    return *reinterpret_cast<const bf16x8*>(p);
}

constexpr int SROW  = 584;
constexpr int DT    = 32;
constexpr int ARENA = 48896;   // dcn phase is the max LDS consumer

// ---------------------------------------------------------------------------
// phase-0 body (R13-verified): blk<288 norm+ref-transpose; 288..431 weights.
// smem needs 18,688 B for the norm branch.
// ---------------------------------------------------------------------------
__device__ __forceinline__ void prologue_body(
    unsigned char* __restrict__ smem, int blk, int t,
    const float* __restrict__ x, const float* __restrict__ ref,
    const float* __restrict__ w1, const float* __restrict__ w2,
    const float* __restrict__ woff, const float* __restrict__ wg,
    const float* __restrict__ wbe, const float* __restrict__ wdcn,
    unsigned short* __restrict__ cc, unsigned short* __restrict__ ccH,
    unsigned short* __restrict__ wt1, unsigned short* __restrict__ wt2,
    unsigned short* __restrict__ wtoff, unsigned short* __restrict__ wtg,
    unsigned short* __restrict__ wtbe, unsigned short* __restrict__ wbdH) {
    if (blk < 288) {
        float* red1  = (float*)smem;          // [4][64]
        float* red2  = red1 + 256;            // [4][64]
        float* rtile = red2 + 256;            // [64][65]

        int b  = blk / 144;
        int p0 = (blk % 144) * 64;
        int px = t & 63;
        int cgI = t >> 6;
        int p  = p0 + px;

        float v[16];
        float s1 = 0.f, s2 = 0.f;
        const float* xb = x + ((size_t)b * NC_ + cgI * 16) * HW_ + p;
        #pragma unroll
        for (int j = 0; j < 16; ++j) {
            v[j] = xb[j * HW_];
            s1 += v[j];
            s2 = fmaf(v[j], v[j], s2);
        }
        red1[cgI * 64 + px] = s1;
        red2[cgI * 64 + px] = s2;

        const float* rb = ref + (size_t)b * SC_ * HW_ + p0 + px;
        #pragma unroll
        for (int it = 0; it < 16; ++it) {
            int ch = it * 4 + cgI;
            rtile[ch * 65 + px] = rb[(size_t)ch * HW_];
        }
        __syncthreads();

        s1 = red1[px] + red1[64 + px] + red1[128 + px] + red1[192 + px];
        s2 = red2[px] + red2[64 + px] + red2[128 + px] + red2[192 + px];
        float mean = s1 * (1.f / 64.f);
        float var  = (s2 - 64.f * mean * mean) * (1.f / 63.f);
        float inv  = 1.f / sqrtf(var + 1e-5f);
        u16x8 pk[2];
        #pragma unroll
        for (int j = 0; j < 16; ++j) {
            float nv = (v[j] - mean) * inv;
            pk[j >> 3][j & 7] = f2bf(nv);
        }
        size_t bp = (size_t)b * HW_ + p;
        *reinterpret_cast<u16x8*>(&cc[bp * 128 + cgI * 16 + 0]) = pk[0];
        *reinterpret_cast<u16x8*>(&cc[bp * 128 + cgI * 16 + 8]) = pk[1];

        {
            int wpx = t >> 2, q = t & 3;
            size_t bp2 = (size_t)b * HW_ + p0 + wpx;
            u16x8 o0, o1, h0, h1;
            #pragma unroll
            for (int j = 0; j < 8; ++j) {
                float v0 = rtile[(q * 16 + j) * 65 + wpx];
                float v1 = rtile[(q * 16 + 8 + j) * 65 + wpx];
                o0[j] = f2bf(v0);    o1[j] = f2bf(v1);
                h0[j] = f2hbits(v0); h1[j] = f2hbits(v1);
            }
            *reinterpret_cast<u16x8*>(&cc[bp2 * 128 + 64 + q * 16 + 0]) = o0;
            *reinterpret_cast<u16x8*>(&cc[bp2 * 128 + 64 + q * 16 + 8]) = o1;
            *reinterpret_cast<u16x8*>(&ccH[bp2 * 64 + q * 16 + 0]) = h0;
            *reinterpret_cast<u16x8*>(&ccH[bp2 * 64 + q * 16 + 8]) = h1;
        }
    } else {
        int idx = (blk - 288) * 256 + t;
        if (idx < 9 * 16 * 128) {
            int tap = idx / (16 * 128), oc = (idx / 128) % 16, ic = idx % 128;
            wt1[idx] = f2bf(w1[(oc * 128 + ic) * 9 + tap]);
        }
        if (idx < 9 * 64 * 32) {
            int tap = idx / (64 * 32), oc = (idx / 32) % 64, ic = idx % 32;
            wt2[idx] = (ic < 16) ? f2bf(w2[(oc * 16 + ic) * 9 + tap]) : (unsigned short)0;
        }
        if (idx < 9 * 32 * 64) {
            int tap = idx / (32 * 64), oc = (idx / 64) % 32, ic = idx % 64;
            wtoff[idx] = (oc < 27) ? f2bf(woff[(oc * 64 + ic) * 9 + tap]) : (unsigned short)0;
        }
        if (idx < 9 * 64 * 64) {
            int tap = idx / (64 * 64), oc = (idx / 64) % 64, ic = idx % 64;
            wtg[idx]  = f2bf(wg [(oc * 64 + ic) * 9 + tap]);
            wtbe[idx] = f2bf(wbe[(oc * 64 + ic) * 9 + tap]);
        }
        if (idx < 64 * 576) {
            int oc = idx / 576, r = idx - oc * 576;
            int tap = r >> 6, ic = r & 63;
            wbdH[idx] = f2hbits(wdcn[oc * 576 + ic * 9 + tap]);
        }
    }
}

// ---------------------------------------------------------------------------
// conv 3x3 body (R13-verified).
// ---------------------------------------------------------------------------
template <int R, int ICS, int ICP, int COLP, int COUT_PAD, int COUT_REAL,
          bool DUAL, bool RELU, int OMODE>
__device__ __forceinline__ void conv_body(
    unsigned short* __restrict__ patch, int blk, int t,
    const unsigned short* __restrict__ in,
    const unsigned short* __restrict__ Wt,
    const unsigned short* __restrict__ Wt2,
    const float* __restrict__ bias, const float* __restrict__ bias2,
    const unsigned short* __restrict__ ccn, float* __restrict__ outF,
    unsigned short* __restrict__ outB) {
    constexpr int NOCT = COUT_PAD / 16;
    constexpr int WPO  = 4 / NOCT;
    constexpr int MTP  = R / WPO;
    constexpr int NKS  = ICP / 32;
    constexpr int NCH8 = ICP / 8;
    constexpr int TY   = 96 / R;
    constexpr int PR   = R + 2;

    int bx = blk % 6;
    int by = (blk / 6) % TY;
    int b  = blk / (6 * TY);
    int x0 = bx * 16, y0 = by * R;

    for (int e = t; e < PR * 18 * NCH8; e += 256) {
        int kc  = e % NCH8;
        int col = (e / NCH8) % 18;
        int row = e / (NCH8 * 18);
        int yy = y0 + row - 1, xx = x0 + col - 1;
        bf16x8 v = (bf16x8){0, 0, 0, 0, 0, 0, 0, 0};
        if (kc * 8 < ICS && (unsigned)yy < (unsigned)H_ && (unsigned)xx < (unsigned)W_) {
            v = ld_frag(&in[((size_t)b * HW_ + yy * W_ + xx) * ICS + kc * 8]);
        }
        *reinterpret_cast<bf16x8*>(&patch[(row * 18 + col) * COLP + kc * 8]) = v;
    }
    __syncthreads();

    int wave = t >> 6, lane = t & 63;
    int fr = lane & 15, fq = lane >> 4;
    int oct  = wave / WPO;
    int widx = wave - oct * WPO;
    int mt0  = widx * MTP;

    f32x4 accA[MTP], accB[MTP];
    #pragma unroll
    for (int i = 0; i < MTP; ++i) {
        accA[i] = (f32x4){0.f, 0.f, 0.f, 0.f};
        accB[i] = (f32x4){0.f, 0.f, 0.f, 0.f};
    }

    constexpr int dyv[9] = {0,0,0,1,1,1,2,2,2};
    constexpr int dxv[9] = {0,1,2,0,1,2,0,1,2};

    #pragma unroll
    for (int tap = 0; tap < 9; ++tap) {
        int dy = dyv[tap], dx = dxv[tap];
        #pragma unroll
        for (int ks = 0; ks < NKS; ++ks) {
            const size_t wo = ((size_t)tap * COUT_PAD + oct * 16 + fr) * ICP + ks * 32 + fq * 8;
            bf16x8 wfA = ld_frag(&Wt[wo]);
            bf16x8 wfB;
            if (DUAL) wfB = ld_frag(&Wt2[wo]);
            #pragma unroll
            for (int i = 0; i < MTP; ++i) {
                bf16x8 pf = ld_frag(&patch[((mt0 + i + dy) * 18 + (fr + dx)) * COLP
                                           + ks * 32 + fq * 8]);
                accA[i] = __builtin_amdgcn_mfma_f32_16x16x32_bf16(wfA, pf, accA[i], 0, 0, 0);
                if (DUAL)
                    accB[i] = __builtin_amdgcn_mfma_f32_16x16x32_bf16(wfB, pf, accB[i], 0, 0, 0);
            }
        }
    }

    #pragma unroll
    for (int i = 0; i < MTP; ++i) {
        int py = mt0 + i;
        if (OMODE == 1) {
            size_t p = (size_t)b * HW_ + (size_t)(y0 + py) * W_ + x0 + fr;
            ushort4 sv;
            #pragma unroll
            for (int j = 0; j < 4; ++j) {
                float v = accA[i][j] + bias[oct * 16 + fq * 4 + j];
                if (RELU) v = fmaxf(v, 0.f);
                ((unsigned short*)&sv)[j] = f2bf(v);
            }
            *reinterpret_cast<ushort4*>(&outB[p * COUT_REAL + oct * 16 + fq * 4]) = sv;
        } else {
            size_t pix = (size_t)b * HW_ + (size_t)(y0 + py) * W_ + x0 + fr;
            ushort4 nv4;
            if (DUAL)
                nv4 = *reinterpret_cast<const ushort4*>(&ccn[pix * 128 + oct * 16 + fq * 4]);
            #pragma unroll
            for (int j = 0; j < 4; ++j) {
                int oc = oct * 16 + fq * 4 + j;
                if (oc >= COUT_REAL) continue;
                size_t off = ((size_t)b * COUT_REAL + oc) * HW_
                           + (size_t)(y0 + py) * W_ + x0 + fr;
                float v = accA[i][j] + bias[oc];
                if (DUAL) {
                    float be = accB[i][j] + bias2[oc];
                    float nv = bf2f(((unsigned short*)&nv4)[j]);
                    outF[off] = fmaf(nv, 1.f + v, be);
                } else {
                    outF[off] = RELU ? fmaxf(v, 0.f) : v;
                }
            }
        }
    }
}

// ---------------------------------------------------------------------------
// dcn body (R13-verified): conv_off in-block + f16 gather + f16 MFMA.
// ---------------------------------------------------------------------------
__device__ __forceinline__ void dcn_body(
    unsigned char* __restrict__ smemArena, int bid, int t,
    const unsigned short* __restrict__ ccH,
    const unsigned short* __restrict__ condT,
    const unsigned short* __restrict__ wtoff,
    const float* __restrict__ b_off,
    const unsigned short* __restrict__ wbdH,
    const float* __restrict__ b_dcn,
    unsigned short* __restrict__ rrT) {
    unsigned short* uS  = (unsigned short*)smemArena;                 // DT*SROW u16
    float*  omL  = (float*)(smemArena + 37376);                       // [32][36]
    ushort4* cwLh = (ushort4*)(smemArena + 37376 + 4608);             // [288]
    int4*    ciL  = (int4*)(smemArena + 37376 + 4608 + 2304);         // [288]

    int swz = (bid & 7) * 72 + (bid >> 3);     // bijective, 576 tiles
    int b   = swz / (HW_ / DT);
    int p0  = (swz % (HW_ / DT)) * DT;
    int y   = p0 / W_, x0 = p0 - y * W_;

    for (int e = t; e < 3 * 34 * 8; e += 256) {
        int kc  = e & 7;
        int col = (e >> 3) % 34;
        int row = (e >> 3) / 34;
        int yy = y + row - 1, xx = x0 + col - 1;
        bf16x8 v = (bf16x8){0, 0, 0, 0, 0, 0, 0, 0};
        if ((unsigned)yy < (unsigned)H_ && (unsigned)xx < (unsigned)W_) {
            v = ld_frag(&condT[((size_t)b * HW_ + yy * W_ + xx) * 64 + kc * 8]);
        }
        *reinterpret_cast<bf16x8*>(&uS[(row * 34 + col) * 72 + kc * 8]) = v;
    }
    __syncthreads();

    int wave = t >> 6, lane = t & 63;
    int fr = lane & 15, fq = lane >> 4;

    {
        int oct = wave & 1, mt = wave >> 1;
        f32x4 acc = (f32x4){0.f, 0.f, 0.f, 0.f};
        constexpr int dyv[9] = {0,0,0,1,1,1,2,2,2};
        constexpr int dxv[9] = {0,1,2,0,1,2,0,1,2};
        #pragma unroll
        for (int tap = 0; tap < 9; ++tap) {
            int dy = dyv[tap], dx = dxv[tap];
            #pragma unroll
            for (int ks = 0; ks < 2; ++ks) {
                bf16x8 wf = ld_frag(&wtoff[((size_t)tap * 32 + oct * 16 + fr) * 64
                                           + ks * 32 + fq * 8]);
                bf16x8 pf = *reinterpret_cast<const bf16x8*>(
                    &uS[(dy * 34 + mt * 16 + fr + dx) * 72 + ks * 32 + fq * 8]);
                acc = __builtin_amdgcn_mfma_f32_16x16x32_bf16(wf, pf, acc, 0, 0, 0);
            }
        }
        int px = mt * 16 + fr;
        float4 o4;
        #pragma unroll
        for (int j = 0; j < 4; ++j) {
            int oc = oct * 16 + fq * 4 + j;
            ((float*)&o4)[j] = acc[j] + (oc < 27 ? b_off[oc] : 0.f);
        }
        *reinterpret_cast<float4*>(&omL[px * 36 + oct * 16 + fq * 4]) = o4;
    }
    __syncthreads();

    for (int e = t; e < DT * 9; e += 256) {
        int pp = e / 9, k = e - pp * 9;
        int p  = p0 + pp;
        int yq = p / W_, xq = p - yq * W_;
        float dy = omL[pp * 36 + 2 * k];
        float dx = omL[pp * 36 + 2 * k + 1];
        float mk = omL[pp * 36 + 18 + k];
        mk = 1.f / (1.f + expf(-mk));

        float py = dy + (float)yq + (float)(k / 3 - 1);
        float px = dx + (float)xq + (float)(k % 3 - 1);
        float fy = floorf(py), fx = floorf(px);
        int   y0c = (int)fy,  x0c = (int)fx;
        float wy = py - fy,   wx = px - fx;

        ushort4 cwh;
        int   ci[4];
        #pragma unroll
        for (int i = 0; i < 4; ++i) {
            int yy = y0c + (i >> 1);
            int xx = x0c + (i & 1);
            bool valid = (yy >= 0) && (yy < H_) && (xx >= 0) && (xx < W_);
            int yc = yy < 0 ? 0 : (yy > H_ - 1 ? H_ - 1 : yy);
            int xc = xx < 0 ? 0 : (xx > W_ - 1 ? W_ - 1 : xx);
            ci[i] = yc * W_ + xc;
            float wyi = (i >> 1) ? wy : (1.f - wy);
            float wxi = (i & 1)  ? wx : (1.f - wx);
            ((unsigned short*)&cwh)[i] = f2hbits(valid ? mk * wyi * wxi : 0.f);
        }
        cwLh[e] = cwh;
        ciL[e] = make_int4(ci[0], ci[1], ci[2], ci[3]);
    }
    __syncthreads();

    {
        const unsigned short* ch = ccH + (size_t)b * HW_ * 64;
        int pp = t >> 3, cg8 = t & 7;
        #pragma unroll
        for (int k = 0; k < 9; ++k) {
            ushort4 cwh = cwLh[pp * 9 + k];
            int4    ci  = ciL[pp * 9 + k];
            f16x8 r0 = *reinterpret_cast<const f16x8*>(&ch[(size_t)ci.x * 64 + cg8 * 8]);
            f16x8 r1 = *reinterpret_cast<const f16x8*>(&ch[(size_t)ci.y * 64 + cg8 * 8]);
            f16x8 r2 = *reinterpret_cast<const f16x8*>(&ch[(size_t)ci.z * 64 + cg8 * 8]);
            f16x8 r3 = *reinterpret_cast<const f16x8*>(&ch[(size_t)ci.w * 64 + cg8 * 8]);
            _Float16 h0 = hfrombits(cwh.x);
            _Float16 h1 = hfrombits(cwh.y);
            _Float16 h2 = hfrombits(cwh.z);
            _Float16 h3 = hfrombits(cwh.w);
            f16x8 s = r0 * h0;
            s += r1 * h1;
            s += r2 * h2;
            s += r3 * h3;
            *reinterpret_cast<f16x8*>(&uS[pp * SROW + k * 64 + cg8 * 8]) = s;
        }
    }
    __syncthreads();

    f32x4 acc0 = (f32x4){0.f, 0.f, 0.f, 0.f};
    f32x4 acc1 = (f32x4){0.f, 0.f, 0.f, 0.f};
    for (int ks = 0; ks < 18; ++ks) {
        f16x8 wf  = *reinterpret_cast<const f16x8*>(
            &wbdH[(size_t)(wave * 16 + fr) * 576 + ks * 32 + fq * 8]);
        f16x8 pf0 = *reinterpret_cast<const f16x8*>(
            &uS[(size_t)fr * SROW + ks * 32 + fq * 8]);
        f16x8 pf1 = *reinterpret_cast<const f16x8*>(
            &uS[(size_t)(16 + fr) * SROW + ks * 32 + fq * 8]);
        acc0 = __builtin_amdgcn_mfma_f32_16x16x32_f16(wf, pf0, acc0, 0, 0, 0);
        acc1 = __builtin_amdgcn_mfma_f32_16x16x32_f16(wf, pf1, acc1, 0, 0, 0);
    }

    {
        size_t p = (size_t)b * HW_ + p0 + fr;
        ushort4 sv0, sv1;
        #pragma unroll
        for (int j = 0; j < 4; ++j) {
            float bo = b_dcn[wave * 16 + fq * 4 + j];
            ((unsigned short*)&sv0)[j] = f2bf(acc0[j] + bo);
            ((unsigned short*)&sv1)[j] = f2bf(acc1[j] + bo);
        }
        *reinterpret_cast<ushort4*>(&rrT[p * 64 + wave * 16 + fq * 4]) = sv0;
        *reinterpret_cast<ushort4*>(&rrT[(p + 16) * 64 + wave * 16 + fq * 4]) = sv1;
    }
}

// ---------------------------------------------------------------------------
// Cooperative mega-kernel: grid = 256 blocks (1/CU guaranteed), phases loop.
// ---------------------------------------------------------------------------
__global__ __launch_bounds__(256)
void spade_mega(const float* __restrict__ x, const float* __restrict__ ref,
                const float* __restrict__ w1, const float* __restrict__ b1,
                const float* __restrict__ w2, const float* __restrict__ b2,
                const float* __restrict__ woff, const float* __restrict__ b_off,
                const float* __restrict__ wdcn, const float* __restrict__ b_dcn,
                const float* __restrict__ wg, const float* __restrict__ b_g,
                const float* __restrict__ wbe, const float* __restrict__ b_be,
                float* __restrict__ out,
                unsigned short* __restrict__ cc, unsigned short* __restrict__ ccH,
                unsigned short* __restrict__ hmidT, unsigned short* __restrict__ condT,
                unsigned short* __restrict__ rrT,
                unsigned short* __restrict__ wt1, unsigned short* __restrict__ wt2,
                unsigned short* __restrict__ wtoff, unsigned short* __restrict__ wtg,
                unsigned short* __restrict__ wtbe, unsigned short* __restrict__ wbdH) {
    cg::grid_group grid = cg::this_grid();
    __shared__ __align__(16) unsigned char smem[ARENA];

    int blk = blockIdx.x;
    int t   = threadIdx.x;

    for (int u = blk; u < 432; u += 256) {
        prologue_body(smem, u, t, x, ref, w1, w2, woff, wg, wbe, wdcn,
                      cc, ccH, wt1, wt2, wtoff, wtg, wtbe, wbdH);
        __syncthreads();
    }
    __threadfence();
    grid.sync();

    for (int u = blk; u < 288; u += 256) {
        conv_body<4, 128, 128, 136, 16, 16, false, true, 1>(
            (unsigned short*)smem, u, t, cc, wt1, nullptr, b1, nullptr,
            nullptr, nullptr, hmidT);
        __syncthreads();
    }
    __threadfence();
    grid.sync();

    for (int u = blk; u < 288; u += 256) {
        conv_body<4, 16, 32, 40, 64, 64, false, true, 1>(
            (unsigned short*)smem, u, t, hmidT, wt2, nullptr, b2, nullptr,
            nullptr, nullptr, condT);
        __syncthreads();
    }
    __threadfence();
    grid.sync();

    for (int u = blk; u < 576; u += 256) {
        dcn_body(smem, u, t, ccH, condT, wtoff, b_off, wbdH, b_dcn, rrT);
        __syncthreads();
    }
    __threadfence();
    grid.sync();

    for (int u = blk; u < 576; u += 256) {
        conv_body<2, 64, 64, 72, 64, 64, true, false, 0>(
            (unsigned short*)smem, u, t, rrT, wtg, wtbe, b_g, b_be, cc, out,
            nullptr);
        __syncthreads();
    }
}

// ---------------------------------------------------------------------------
// Fallback standalone kernels (the verified R13 pipeline, via shared bodies).
// ---------------------------------------------------------------------------
__global__ __launch_bounds__(256)
void prologue_k(const float* x, const float* ref,
                const float* w1, const float* w2, const float* woff,
                const float* wg, const float* wbe, const float* wdcn,
                unsigned short* cc, unsigned short* ccH,
                unsigned short* wt1, unsigned short* wt2, unsigned short* wtoff,
                unsigned short* wtg, unsigned short* wtbe, unsigned short* wbdH) {
    __shared__ __align__(16) unsigned char smem[18688];
    prologue_body(smem, blockIdx.x, threadIdx.x, x, ref, w1, w2, woff, wg,
                  wbe, wdcn, cc, ccH, wt1, wt2, wtoff, wtg, wtbe, wbdH);
}

template <int R, int ICS, int ICP, int COLP, int COUT_PAD, int COUT_REAL,
          bool DUAL, bool RELU, int OMODE>
__global__ __launch_bounds__(256)
void conv_k(const unsigned short* in, const unsigned short* Wt,
            const unsigned short* Wt2, const float* bias, const float* bias2,
            const unsigned short* ccn, float* outF, unsigned short* outB) {
    __shared__ unsigned short patch[(R + 2) * 18 * COLP];
    conv_body<R, ICS, ICP, COLP, COUT_PAD, COUT_REAL, DUAL, RELU, OMODE>(
        patch, blockIdx.x, threadIdx.x, in, Wt, Wt2, bias, bias2, ccn, outF, outB);
}

__global__ __launch_bounds__(256)
void dcn_k(const unsigned short* ccH, const unsigned short* condT,
           const unsigned short* wtoff, const float* b_off,
           const unsigned short* wbdH, const float* b_dcn,
           unsigned short* rrT) {
    __shared__ __align__(16) unsigned char smem[ARENA];
    dcn_body(smem, blockIdx.x, threadIdx.x, ccH, condT, wtoff, b_off, wbdH,
             b_dcn, rrT);
}

} // namespace

// ---------------------------------------------------------------------------
extern "C" void kernel_launch(void* const* d_in, const int* in_sizes, int n_in,
                              void* d_out, int out_size, void* d_ws, size_t ws_size,
                              hipStream_t stream) {
    (void)in_sizes; (void)n_in; (void)out_size; (void)ws_size;

    const float* x     = (const float*)d_in[0];
    const float* ref   = (const float*)d_in[1];
    const float* w1    = (const float*)d_in[2];
    const float* b1    = (const float*)d_in[3];
    const float* w2    = (const float*)d_in[4];
    const float* b2    = (const float*)d_in[5];
    const float* w_off = (const float*)d_in[6];
    const float* b_off = (const float*)d_in[7];
    const float* w_dcn = (const float*)d_in[8];
    const float* b_dcn = (const float*)d_in[9];
    const float* w_g   = (const float*)d_in[10];
    const float* b_g   = (const float*)d_in[11];
    const float* w_be  = (const float*)d_in[12];
    const float* b_be  = (const float*)d_in[13];

    float* out = (float*)d_out;

    unsigned short* cc    = (unsigned short*)d_ws;           // [b][p][128] bf16
    unsigned short* ccH   = cc    + 2359296;                 // [b][p][64]  f16
    unsigned short* hmidT = ccH   + 1179648;                 // [b][p][16]  bf16
    unsigned short* condT = hmidT + 294912;                  // [b][p][64]  bf16
    unsigned short* rrT   = condT + 1179648;                 // [b][p][64]  bf16
    unsigned short* wt1   = rrT   + 1179648;
    unsigned short* wt2   = wt1   + 18432;
    unsigned short* wtoff = wt2   + 18432;
    unsigned short* wtg   = wtoff + 18432;
    unsigned short* wtbe  = wtg   + 36864;
    unsigned short* wbdH  = wtbe  + 36864;

    void* args[] = {
        (void*)&x, (void*)&ref, (void*)&w1, (void*)&b1, (void*)&w2, (void*)&b2,
        (void*)&w_off, (void*)&b_off, (void*)&w_dcn, (void*)&b_dcn,
        (void*)&w_g, (void*)&b_g, (void*)&w_be, (void*)&b_be, (void*)&out,
        (void*)&cc, (void*)&ccH, (void*)&hmidT, (void*)&condT, (void*)&rrT,
        (void*)&wt1, (void*)&wt2, (void*)&wtoff, (void*)&wtg, (void*)&wtbe,
        (void*)&wbdH
    };

    hipError_t err = hipLaunchCooperativeKernel(
        (const void*)spade_mega, dim3(256), dim3(256), args, 0, stream);

    if (err != hipSuccess) {
        // Deterministic fallback: the verified 5-kernel pipeline (R13).
        prologue_k<<<432, 256, 0, stream>>>(x, ref, w1, w2, w_off, w_g, w_be,
                                            w_dcn, cc, ccH, wt1, wt2, wtoff,
                                            wtg, wtbe, wbdH);
        conv_k<4, 128, 128, 136, 16, 16, false, true, 1>
            <<<288, 256, 0, stream>>>(cc, wt1, nullptr, b1, nullptr, nullptr,
                                      nullptr, hmidT);
        conv_k<4, 16, 32, 40, 64, 64, false, true, 1>
            <<<288, 256, 0, stream>>>(hmidT, wt2, nullptr, b2, nullptr,
                                      nullptr, nullptr, condT);
        dcn_k<<<576, 256, 0, stream>>>(ccH, condT, wtoff, b_off, wbdH, b_dcn,
                                       rrT);
        conv_k<2, 64, 64, 72, 64, 64, true, false, 0>
            <<<576, 256, 0, stream>>>(rrT, wtg, wtbe, b_g, b_be, cc, out,
                                      nullptr);
    }
}

// Round 17
// 75.848 us; speedup vs baseline: 4.0627x; 4.0627x over previous
//
#include <hip/hip_runtime.h>
#include <math.h>

namespace {

typedef __attribute__((ext_vector_type(8))) short          bf16x8;
typedef __attribute__((ext_vector_type(8))) unsigned short u16x8;
typedef __attribute__((ext_vector_type(8))) _Float16       f16x8;
typedef __attribute__((ext_vector_type(4))) float          f32x4;

constexpr int B_  = 2;
constexpr int H_  = 96;
constexpr int W_  = 96;
constexpr int HW_ = H_ * W_;
constexpr int NC_ = 64;
constexpr int SC_ = 64;

__device__ inline unsigned short f2bf(float f) {
    union { float f; unsigned u; } v; v.f = f;
    unsigned r = v.u + 0x7FFFu + ((v.u >> 16) & 1u);
    return (unsigned short)(r >> 16);
}
__device__ inline float bf2f(unsigned short s) {
    union { unsigned u; float f; } v; v.u = ((unsigned)s) << 16; return v.f;
}
__device__ inline unsigned short f2hbits(float f) {
    union { _Float16 h; unsigned short u; } s; s.h = (_Float16)f; return s.u;
}
__device__ inline _Float16 hfrombits(unsigned short u) {
    union { _Float16 h; unsigned short u; } s; s.u = u; return s.h;
}
__device__ inline bf16x8 ld_frag(const unsigned short* p) {
    return *reinterpret_cast<const bf16x8*>(p);
}

constexpr int SROW  = 584;
constexpr int DT    = 32;
constexpr int ARENA = 48896;

// ---------------------------------------------------------------------------
// K0: weight prep (grid 144). Must finish before K1 (conv1 reads wt1).
// ---------------------------------------------------------------------------
__global__ __launch_bounds__(256)
void wprep_k(const float* __restrict__ w1, const float* __restrict__ w2,
             const float* __restrict__ woff, const float* __restrict__ wg,
             const float* __restrict__ wbe, const float* __restrict__ wdcn,
             unsigned short* __restrict__ wt1, unsigned short* __restrict__ wt2,
             unsigned short* __restrict__ wtoff, unsigned short* __restrict__ wtg,
             unsigned short* __restrict__ wtbe, unsigned short* __restrict__ wbdH) {
    int idx = blockIdx.x * 256 + threadIdx.x;
    if (idx < 9 * 16 * 128) {
        int tap = idx / (16 * 128), oc = (idx / 128) % 16, ic = idx % 128;
        wt1[idx] = f2bf(w1[(oc * 128 + ic) * 9 + tap]);
    }
    if (idx < 9 * 64 * 32) {
        int tap = idx / (64 * 32), oc = (idx / 32) % 64, ic = idx % 32;
        wt2[idx] = (ic < 16) ? f2bf(w2[(oc * 16 + ic) * 9 + tap]) : (unsigned short)0;
    }
    if (idx < 9 * 32 * 64) {
        int tap = idx / (32 * 64), oc = (idx / 64) % 32, ic = idx % 64;
        wtoff[idx] = (oc < 27) ? f2bf(woff[(oc * 64 + ic) * 9 + tap]) : (unsigned short)0;
    }
    if (idx < 9 * 64 * 64) {
        int tap = idx / (64 * 64), oc = (idx / 64) % 64, ic = idx % 64;
        wtg[idx]  = f2bf(wg [(oc * 64 + ic) * 9 + tap]);
        wtbe[idx] = f2bf(wbe[(oc * 64 + ic) * 9 + tap]);
    }
    if (idx < 64 * 576) {
        int oc = idx / 576, r = idx - oc * 576;
        int tap = r >> 6, ic = r & 63;
        wbdH[idx] = f2hbits(wdcn[oc * 576 + ic * 9 + tap]);
    }
}

// ---------------------------------------------------------------------------
// K1: grid 576.
//  blk   0..287: in-block norm + conv1 MFMA -> hmidT; interior norm -> ccN
//  blk 288..575: ref transpose -> ccH (f16)
// ---------------------------------------------------------------------------
__global__ __launch_bounds__(256)
void fused1_k(const float* __restrict__ x, const float* __restrict__ ref,
              const float* __restrict__ b1,
              const unsigned short* __restrict__ wt1,
              unsigned short* __restrict__ ccN, unsigned short* __restrict__ ccH,
              unsigned short* __restrict__ hmidT) {
    __shared__ __align__(16) unsigned char smem[32768];

    int blk = blockIdx.x;
    int t   = threadIdx.x;

    if (blk < 288) {
        unsigned short* patch = (unsigned short*)smem;        // [6*18][136]
        float2* psum = (float2*)(smem + 6 * 18 * 136 * 2);    // [108][2]

        int bx = blk % 6, by = (blk / 6) % 24, b = blk / 144;
        int x0 = bx * 16, y0 = by * 4;

        // step A: per-pixel norm, 2 threads/pixel (108 px)
        int u = t >> 1, half = t & 1;
        bool active = (u < 108);
        float xv[32];
        int row = 0, col = 0, yy = 0, xx = 0;
        bool inimg = false;
        if (active) {
            row = u / 18; col = u - row * 18;
            yy = y0 + row - 1; xx = x0 + col - 1;
            inimg = ((unsigned)yy < (unsigned)H_) && ((unsigned)xx < (unsigned)W_);
            float s1 = 0.f, s2 = 0.f;
            if (inimg) {
                const float* xp = x + ((size_t)b * NC_ + half * 32) * HW_ + yy * W_ + xx;
                #pragma unroll
                for (int j = 0; j < 32; ++j) {
                    xv[j] = xp[j * HW_];
                    s1 += xv[j];
                    s2 = fmaf(xv[j], xv[j], s2);
                }
            }
            psum[u * 2 + half] = make_float2(s1, s2);
        }
        __syncthreads();
        if (active) {
            float2 pa = psum[u * 2 + 0], pb = psum[u * 2 + 1];
            float s1 = pa.x + pb.x, s2 = pa.y + pb.y;
            float mean = s1 * (1.f / 64.f);
            float var  = (s2 - 64.f * mean * mean) * (1.f / 63.f);
            float inv  = 1.f / sqrtf(var + 1e-5f);
            u16x8 pk[4];
            #pragma unroll
            for (int j = 0; j < 32; ++j) {
                float nv = inimg ? (xv[j] - mean) * inv : 0.f;
                pk[j >> 3][j & 7] = f2bf(nv);
            }
            unsigned short* pp = &patch[(row * 18 + col) * 136 + half * 32];
            #pragma unroll
            for (int q = 0; q < 4; ++q)
                *reinterpret_cast<u16x8*>(pp + q * 8) = pk[q];
            if (row >= 1 && row <= 4 && col >= 1 && col <= 16) {
                size_t p = (size_t)b * HW_ + yy * W_ + xx;
                #pragma unroll
                for (int q = 0; q < 4; ++q)
                    *reinterpret_cast<u16x8*>(&ccN[p * 64 + half * 32 + q * 8]) = pk[q];
            }
        }

        // step C: ref half of patch (ch 64..127)
        for (int e = t; e < 6 * 64; e += 256) {
            int rr = e >> 6, ch = e & 63;
            int yy2 = y0 + rr - 1;
            unsigned short tmp[18];
            if ((unsigned)yy2 < (unsigned)H_) {
                const float* rp = ref + ((size_t)b * SC_ + ch) * HW_ + yy2 * W_;
                #pragma unroll
                for (int c2 = 0; c2 < 18; ++c2) {
                    int xx2 = x0 + c2 - 1;
                    tmp[c2] = ((unsigned)xx2 < (unsigned)W_) ? f2bf(rp[xx2])
                                                             : (unsigned short)0;
                }
            } else {
                #pragma unroll
                for (int c2 = 0; c2 < 18; ++c2) tmp[c2] = 0;
            }
            #pragma unroll
            for (int c2 = 0; c2 < 18; ++c2)
                patch[(rr * 18 + c2) * 136 + 64 + ch] = tmp[c2];
        }
        __syncthreads();

        // conv1 MFMA (wt1 produced by K0 — no intra-kernel race)
        int wave = t >> 6, lane = t & 63;
        int fr = lane & 15, fq = lane >> 4;

        f32x4 acc = (f32x4){0.f, 0.f, 0.f, 0.f};
        constexpr int dyv[9] = {0,0,0,1,1,1,2,2,2};
        constexpr int dxv[9] = {0,1,2,0,1,2,0,1,2};
        #pragma unroll
        for (int tap = 0; tap < 9; ++tap) {
            int dy = dyv[tap], dx = dxv[tap];
            #pragma unroll
            for (int ks = 0; ks < 4; ++ks) {
                bf16x8 wf = ld_frag(&wt1[((size_t)tap * 16 + fr) * 128 + ks * 32 + fq * 8]);
                bf16x8 pf = ld_frag(&patch[((wave + dy) * 18 + (fr + dx)) * 136
                                           + ks * 32 + fq * 8]);
                acc = __builtin_amdgcn_mfma_f32_16x16x32_bf16(wf, pf, acc, 0, 0, 0);
            }
        }
        size_t p = (size_t)b * HW_ + (size_t)(y0 + wave) * W_ + x0 + fr;
        ushort4 sv;
        #pragma unroll
        for (int j = 0; j < 4; ++j) {
            float v = fmaxf(acc[j] + b1[fq * 4 + j], 0.f);
            ((unsigned short*)&sv)[j] = f2bf(v);
        }
        *reinterpret_cast<ushort4*>(&hmidT[p * 16 + fq * 4]) = sv;

    } else {
        // ref transpose -> ccH
        float* rtile = (float*)smem;       // [64][65]
        int blk2 = blk - 288;
        int b  = blk2 / 144;
        int p0 = (blk2 % 144) * 64;
        int px = t & 63;
        int cgI = t >> 6;

        const float* rb = ref + (size_t)b * SC_ * HW_ + p0 + px;
        #pragma unroll
        for (int it = 0; it < 16; ++it) {
            int ch = it * 4 + cgI;
            rtile[ch * 65 + px] = rb[(size_t)ch * HW_];
        }
        __syncthreads();

        int wpx = t >> 2, q = t & 3;
        size_t bp2 = (size_t)b * HW_ + p0 + wpx;
        u16x8 h0, h1;
        #pragma unroll
        for (int j = 0; j < 8; ++j) {
            h0[j] = f2hbits(rtile[(q * 16 + j) * 65 + wpx]);
            h1[j] = f2hbits(rtile[(q * 16 + 8 + j) * 65 + wpx]);
        }
        *reinterpret_cast<u16x8*>(&ccH[bp2 * 64 + q * 16 + 0]) = h0;
        *reinterpret_cast<u16x8*>(&ccH[bp2 * 64 + q * 16 + 8]) = h1;
    }
}

// ---------------------------------------------------------------------------
// conv 3x3 (R13-verified). OMODE 0 + DUAL: final epilogue, ccn = ccN [p][64].
// ---------------------------------------------------------------------------
template <int R, int ICS, int ICP, int COLP, int COUT_PAD, int COUT_REAL,
          bool DUAL, bool RELU, int OMODE>
__global__ __launch_bounds__(256)
void conv_k(const unsigned short* __restrict__ in,
            const unsigned short* __restrict__ Wt,
            const unsigned short* __restrict__ Wt2,
            const float* __restrict__ bias, const float* __restrict__ bias2,
            const unsigned short* __restrict__ ccn, float* __restrict__ outF,
            unsigned short* __restrict__ outB) {
    constexpr int NOCT = COUT_PAD / 16;
    constexpr int WPO  = 4 / NOCT;
    constexpr int MTP  = R / WPO;
    constexpr int NKS  = ICP / 32;
    constexpr int NCH8 = ICP / 8;
    constexpr int TY   = 96 / R;
    constexpr int PR   = R + 2;

    __shared__ unsigned short patch[PR * 18 * COLP];

    int t   = threadIdx.x;
    int blk = blockIdx.x;
    int bx  = blk % 6;
    int by  = (blk / 6) % TY;
    int b   = blk / (6 * TY);
    int x0  = bx * 16, y0 = by * R;

    for (int e = t; e < PR * 18 * NCH8; e += 256) {
        int kc  = e % NCH8;
        int col = (e / NCH8) % 18;
        int row = e / (NCH8 * 18);
        int yy = y0 + row - 1, xx = x0 + col - 1;
        bf16x8 v = (bf16x8){0, 0, 0, 0, 0, 0, 0, 0};
        if (kc * 8 < ICS && (unsigned)yy < (unsigned)H_ && (unsigned)xx < (unsigned)W_) {
            v = ld_frag(&in[((size_t)b * HW_ + yy * W_ + xx) * ICS + kc * 8]);
        }
        *reinterpret_cast<bf16x8*>(&patch[(row * 18 + col) * COLP + kc * 8]) = v;
    }
    __syncthreads();

    int wave = t >> 6, lane = t & 63;
    int fr = lane & 15, fq = lane >> 4;
    int oct  = wave / WPO;
    int widx = wave - oct * WPO;
    int mt0  = widx * MTP;

    f32x4 accA[MTP], accB[MTP];
    #pragma unroll
    for (int i = 0; i < MTP; ++i) {
        accA[i] = (f32x4){0.f, 0.f, 0.f, 0.f};
        accB[i] = (f32x4){0.f, 0.f, 0.f, 0.f};
    }

    constexpr int dyv[9] = {0,0,0,1,1,1,2,2,2};
    constexpr int dxv[9] = {0,1,2,0,1,2,0,1,2};

    #pragma unroll
    for (int tap = 0; tap < 9; ++tap) {
        int dy = dyv[tap], dx = dxv[tap];
        #pragma unroll
        for (int ks = 0; ks < NKS; ++ks) {
            const size_t wo = ((size_t)tap * COUT_PAD + oct * 16 + fr) * ICP + ks * 32 + fq * 8;
            bf16x8 wfA = ld_frag(&Wt[wo]);
            bf16x8 wfB;
            if (DUAL) wfB = ld_frag(&Wt2[wo]);
            #pragma unroll
            for (int i = 0; i < MTP; ++i) {
                bf16x8 pf = ld_frag(&patch[((mt0 + i + dy) * 18 + (fr + dx)) * COLP
                                           + ks * 32 + fq * 8]);
                accA[i] = __builtin_amdgcn_mfma_f32_16x16x32_bf16(wfA, pf, accA[i], 0, 0, 0);
                if (DUAL)
                    accB[i] = __builtin_amdgcn_mfma_f32_16x16x32_bf16(wfB, pf, accB[i], 0, 0, 0);
            }
        }
    }

    #pragma unroll
    for (int i = 0; i < MTP; ++i) {
        int py = mt0 + i;
        if (OMODE == 1) {
            size_t p = (size_t)b * HW_ + (size_t)(y0 + py) * W_ + x0 + fr;
            ushort4 sv;
            #pragma unroll
            for (int j = 0; j < 4; ++j) {
                float v = accA[i][j] + bias[oct * 16 + fq * 4 + j];
                if (RELU) v = fmaxf(v, 0.f);
                ((unsigned short*)&sv)[j] = f2bf(v);
            }
            *reinterpret_cast<ushort4*>(&outB[p * COUT_REAL + oct * 16 + fq * 4]) = sv;
        } else {
            size_t pix = (size_t)b * HW_ + (size_t)(y0 + py) * W_ + x0 + fr;
            ushort4 nv4;
            if (DUAL)
                nv4 = *reinterpret_cast<const ushort4*>(&ccn[pix * 64 + oct * 16 + fq * 4]);
            #pragma unroll
            for (int j = 0; j < 4; ++j) {
                int oc = oct * 16 + fq * 4 + j;
                if (oc >= COUT_REAL) continue;
                size_t off = ((size_t)b * COUT_REAL + oc) * HW_
                           + (size_t)(y0 + py) * W_ + x0 + fr;
                float v = accA[i][j] + bias[oc];
                if (DUAL) {
                    float be = accB[i][j] + bias2[oc];
                    float nv = bf2f(((unsigned short*)&nv4)[j]);
                    outF[off] = fmaf(nv, 1.f + v, be);
                } else {
                    outF[off] = RELU ? fmaxf(v, 0.f) : v;
                }
            }
        }
    }
}

// ---------------------------------------------------------------------------
// dcn kernel (R13-verified): conv_off in-block + f16 gather + f16 MFMA.
// ---------------------------------------------------------------------------
__global__ __launch_bounds__(256)
void dcn_k(const unsigned short* __restrict__ ccH,
           const unsigned short* __restrict__ condT,
           const unsigned short* __restrict__ wtoff,
           const float* __restrict__ b_off,
           const unsigned short* __restrict__ wbdH,
           const float* __restrict__ b_dcn,
           unsigned short* __restrict__ rrT) {
    __shared__ __align__(16) unsigned char smemArena[ARENA];
    unsigned short* uS  = (unsigned short*)smemArena;
    float*  omL  = (float*)(smemArena + 37376);
    ushort4* cwLh = (ushort4*)(smemArena + 37376 + 4608);
    int4*    ciL  = (int4*)(smemArena + 37376 + 4608 + 2304);

    int t = threadIdx.x;
    int bid = blockIdx.x;
    int swz = (bid & 7) * 72 + (bid >> 3);
    int b   = swz / (HW_ / DT);
    int p0  = (swz % (HW_ / DT)) * DT;
    int y   = p0 / W_, x0 = p0 - y * W_;

    for (int e = t; e < 3 * 34 * 8; e += 256) {
        int kc  = e & 7;
        int col = (e >> 3) % 34;
        int row = (e >> 3) / 34;
        int yy = y + row - 1, xx = x0 + col - 1;
        bf16x8 v = (bf16x8){0, 0, 0, 0, 0, 0, 0, 0};
        if ((unsigned)yy < (unsigned)H_ && (unsigned)xx < (unsigned)W_) {
            v = ld_frag(&condT[((size_t)b * HW_ + yy * W_ + xx) * 64 + kc * 8]);
        }
        *reinterpret_cast<bf16x8*>(&uS[(row * 34 + col) * 72 + kc * 8]) = v;
    }
    __syncthreads();

    int wave = t >> 6, lane = t & 63;
    int fr = lane & 15, fq = lane >> 4;

    {
        int oct = wave & 1, mt = wave >> 1;
        f32x4 acc = (f32x4){0.f, 0.f, 0.f, 0.f};
        constexpr int dyv[9] = {0,0,0,1,1,1,2,2,2};
        constexpr int dxv[9] = {0,1,2,0,1,2,0,1,2};
        #pragma unroll
        for (int tap = 0; tap < 9; ++tap) {
            int dy = dyv[tap], dx = dxv[tap];
            #pragma unroll
            for (int ks = 0; ks < 2; ++ks) {
                bf16x8 wf = ld_frag(&wtoff[((size_t)tap * 32 + oct * 16 + fr) * 64
                                           + ks * 32 + fq * 8]);
                bf16x8 pf = *reinterpret_cast<const bf16x8*>(
                    &uS[(dy * 34 + mt * 16 + fr + dx) * 72 + ks * 32 + fq * 8]);
                acc = __builtin_amdgcn_mfma_f32_16x16x32_bf16(wf, pf, acc, 0, 0, 0);
            }
        }
        int px = mt * 16 + fr;
        float4 o4;
        #pragma unroll
        for (int j = 0; j < 4; ++j) {
            int oc = oct * 16 + fq * 4 + j;
            ((float*)&o4)[j] = acc[j] + (oc < 27 ? b_off[oc] : 0.f);
        }
        *reinterpret_cast<float4*>(&omL[px * 36 + oct * 16 + fq * 4]) = o4;
    }
    __syncthreads();

    for (int e = t; e < DT * 9; e += 256) {
        int pp = e / 9, k = e - pp * 9;
        int p  = p0 + pp;
        int yq = p / W_, xq = p - yq * W_;
        float dy = omL[pp * 36 + 2 * k];
        float dx = omL[pp * 36 + 2 * k + 1];
        float mk = omL[pp * 36 + 18 + k];
        mk = 1.f / (1.f + expf(-mk));

        float py = dy + (float)yq + (float)(k / 3 - 1);
        float px = dx + (float)xq + (float)(k % 3 - 1);
        float fy = floorf(py), fx = floorf(px);
        int   y0c = (int)fy,  x0c = (int)fx;
        float wy = py - fy,   wx = px - fx;

        ushort4 cwh;
        int   ci[4];
        #pragma unroll
        for (int i = 0; i < 4; ++i) {
            int yy = y0c + (i >> 1);
            int xx = x0c + (i & 1);
            bool valid = (yy >= 0) && (yy < H_) && (xx >= 0) && (xx < W_);
            int yc = yy < 0 ? 0 : (yy > H_ - 1 ? H_ - 1 : yy);
            int xc = xx < 0 ? 0 : (xx > W_ - 1 ? W_ - 1 : xx);
            ci[i] = yc * W_ + xc;
            float wyi = (i >> 1) ? wy : (1.f - wy);
            float wxi = (i & 1)  ? wx : (1.f - wx);
            ((unsigned short*)&cwh)[i] = f2hbits(valid ? mk * wyi * wxi : 0.f);
        }
        cwLh[e] = cwh;
        ciL[e] = make_int4(ci[0], ci[1], ci[2], ci[3]);
    }
    __syncthreads();

    {
        const unsigned short* ch = ccH + (size_t)b * HW_ * 64;
        int pp = t >> 3, cg8 = t & 7;
        #pragma unroll
        for (int k = 0; k < 9; ++k) {
            ushort4 cwh = cwLh[pp * 9 + k];
            int4    ci  = ciL[pp * 9 + k];
            f16x8 r0 = *reinterpret_cast<const f16x8*>(&ch[(size_t)ci.x * 64 + cg8 * 8]);
            f16x8 r1 = *reinterpret_cast<const f16x8*>(&ch[(size_t)ci.y * 64 + cg8 * 8]);
            f16x8 r2 = *reinterpret_cast<const f16x8*>(&ch[(size_t)ci.z * 64 + cg8 * 8]);
            f16x8 r3 = *reinterpret_cast<const f16x8*>(&ch[(size_t)ci.w * 64 + cg8 * 8]);
            _Float16 h0 = hfrombits(cwh.x);
            _Float16 h1 = hfrombits(cwh.y);
            _Float16 h2 = hfrombits(cwh.z);
            _Float16 h3 = hfrombits(cwh.w);
            f16x8 s = r0 * h0;
            s += r1 * h1;
            s += r2 * h2;
            s += r3 * h3;
            *reinterpret_cast<f16x8*>(&uS[pp * SROW + k * 64 + cg8 * 8]) = s;
        }
    }
    __syncthreads();

    f32x4 acc0 = (f32x4){0.f, 0.f, 0.f, 0.f};
    f32x4 acc1 = (f32x4){0.f, 0.f, 0.f, 0.f};
    for (int ks = 0; ks < 18; ++ks) {
        f16x8 wf  = *reinterpret_cast<const f16x8*>(
            &wbdH[(size_t)(wave * 16 + fr) * 576 + ks * 32 + fq * 8]);
        f16x8 pf0 = *reinterpret_cast<const f16x8*>(
            &uS[(size_t)fr * SROW + ks * 32 + fq * 8]);
        f16x8 pf1 = *reinterpret_cast<const f16x8*>(
            &uS[(size_t)(16 + fr) * SROW + ks * 32 + fq * 8]);
        acc0 = __builtin_amdgcn_mfma_f32_16x16x32_f16(wf, pf0, acc0, 0, 0, 0);
        acc1 = __builtin_amdgcn_mfma_f32_16x16x32_f16(wf, pf1, acc1, 0, 0, 0);
    }

    {
        size_t p = (size_t)b * HW_ + p0 + fr;
        ushort4 sv0, sv1;
        #pragma unroll
        for (int j = 0; j < 4; ++j) {
            float bo = b_dcn[wave * 16 + fq * 4 + j];
            ((unsigned short*)&sv0)[j] = f2bf(acc0[j] + bo);
            ((unsigned short*)&sv1)[j] = f2bf(acc1[j] + bo);
        }
        *reinterpret_cast<ushort4*>(&rrT[p * 64 + wave * 16 + fq * 4]) = sv0;
        *reinterpret_cast<ushort4*>(&rrT[(p + 16) * 64 + wave * 16 + fq * 4]) = sv1;
    }
}

} // namespace

// ---------------------------------------------------------------------------
extern "C" void kernel_launch(void* const* d_in, const int* in_sizes, int n_in,
                              void* d_out, int out_size, void* d_ws, size_t ws_size,
                              hipStream_t stream) {
    (void)in_sizes; (void)n_in; (void)out_size; (void)ws_size;

    const float* x     = (const float*)d_in[0];
    const float* ref   = (const float*)d_in[1];
    const float* w1    = (const float*)d_in[2];
    const float* b1    = (const float*)d_in[3];
    const float* w2    = (const float*)d_in[4];
    const float* b2    = (const float*)d_in[5];
    const float* w_off = (const float*)d_in[6];
    const float* b_off = (const float*)d_in[7];
    const float* w_dcn = (const float*)d_in[8];
    const float* b_dcn = (const float*)d_in[9];
    const float* w_g   = (const float*)d_in[10];
    const float* b_g   = (const float*)d_in[11];
    const float* w_be  = (const float*)d_in[12];
    const float* b_be  = (const float*)d_in[13];

    float* out = (float*)d_out;

    unsigned short* ccN   = (unsigned short*)d_ws;           // [b][p][64] bf16
    unsigned short* ccH   = ccN   + 1179648;                 // [b][p][64] f16
    unsigned short* hmidT = ccH   + 1179648;                 // [b][p][16] bf16
    unsigned short* condT = hmidT + 294912;                  // [b][p][64] bf16
    unsigned short* rrT   = condT + 1179648;                 // [b][p][64] bf16
    unsigned short* wt1   = rrT   + 1179648;
    unsigned short* wt2   = wt1   + 18432;
    unsigned short* wtoff = wt2   + 18432;
    unsigned short* wtg   = wtoff + 18432;
    unsigned short* wtbe  = wtg   + 36864;
    unsigned short* wbdH  = wtbe  + 36864;

    // K0: weight prep (conv1 in K1 reads wt1 -> must be a separate launch)
    wprep_k<<<144, 256, 0, stream>>>(w1, w2, w_off, w_g, w_be, w_dcn,
                                     wt1, wt2, wtoff, wtg, wtbe, wbdH);

    // K1: fused norm+conv1 | ref transpose
    fused1_k<<<576, 256, 0, stream>>>(x, ref, b1, wt1, ccN, ccH, hmidT);

    // K2: conv2
    conv_k<4, 16, 32, 40, 64, 64, false, true, 1>
        <<<288, 256, 0, stream>>>(hmidT, wt2, nullptr, b2, nullptr, nullptr,
                                  nullptr, condT);

    // K3: dcn (+conv_off)
    dcn_k<<<576, 256, 0, stream>>>(ccH, condT, wtoff, b_off, wbdH, b_dcn, rrT);

    // K4: final (gamma/beta DUAL + affine epilogue; norm from ccN)
    conv_k<2, 64, 64, 72, 64, 64, true, false, 0>
        <<<576, 256, 0, stream>>>(rrT, wtg, wtbe, b_g, b_be, ccN, out, nullptr);
}

// Round 18
// 67.531 us; speedup vs baseline: 4.5630x; 1.1232x over previous
//
#include <hip/hip_runtime.h>
#include <math.h>

namespace {

typedef __attribute__((ext_vector_type(8))) short          bf16x8;
typedef __attribute__((ext_vector_type(8))) unsigned short u16x8;
typedef __attribute__((ext_vector_type(8))) _Float16       f16x8;
typedef __attribute__((ext_vector_type(4))) float          f32x4;

constexpr int B_  = 2;
constexpr int H_  = 96;
constexpr int W_  = 96;
constexpr int HW_ = H_ * W_;
constexpr int NC_ = 64;
constexpr int SC_ = 64;

__device__ inline unsigned short f2bf(float f) {
    union { float f; unsigned u; } v; v.f = f;
    unsigned r = v.u + 0x7FFFu + ((v.u >> 16) & 1u);
    return (unsigned short)(r >> 16);
}
__device__ inline float bf2f(unsigned short s) {
    union { unsigned u; float f; } v; v.u = ((unsigned)s) << 16; return v.f;
}
__device__ inline unsigned short f2hbits(float f) {
    union { _Float16 h; unsigned short u; } s; s.h = (_Float16)f; return s.u;
}
__device__ inline _Float16 hfrombits(unsigned short u) {
    union { _Float16 h; unsigned short u; } s; s.u = u; return s.h;
}
__device__ inline bf16x8 ld_frag(const unsigned short* p) {
    return *reinterpret_cast<const bf16x8*>(p);
}

// ---------------------------------------------------------------------------
// prologue (grid 432): blocks 0..287 norm (bf16 only -> cc) + ref transpose
// (cc bf16 + ccH f16); blocks 288..431 weight prep.  NO f32 nrm buffer.
// ---------------------------------------------------------------------------
__global__ __launch_bounds__(256)
void prologue(const float* __restrict__ x, const float* __restrict__ ref,
              const float* __restrict__ w1, const float* __restrict__ w2,
              const float* __restrict__ woff, const float* __restrict__ wg,
              const float* __restrict__ wbe, const float* __restrict__ wdcn,
              unsigned short* __restrict__ cc, unsigned short* __restrict__ ccH,
              unsigned short* __restrict__ wt1, unsigned short* __restrict__ wt2,
              unsigned short* __restrict__ wtoff, unsigned short* __restrict__ wtg,
              unsigned short* __restrict__ wtbe, unsigned short* __restrict__ wbdH) {
    __shared__ float red1[4][64];
    __shared__ float red2[4][64];
    __shared__ float rtile[64][65];

    int blk = blockIdx.x;
    int t   = threadIdx.x;

    if (blk < 288) {
        int b  = blk / 144;
        int p0 = (blk % 144) * 64;
        int px = t & 63;
        int cg = t >> 6;
        int p  = p0 + px;

        float v[16];
        float s1 = 0.f, s2 = 0.f;
        const float* xb = x + ((size_t)b * NC_ + cg * 16) * HW_ + p;
        #pragma unroll
        for (int j = 0; j < 16; ++j) {
            v[j] = xb[j * HW_];
            s1 += v[j];
            s2 = fmaf(v[j], v[j], s2);
        }
        red1[cg][px] = s1;
        red2[cg][px] = s2;

        const float* rb = ref + (size_t)b * SC_ * HW_ + p0 + px;
        #pragma unroll
        for (int it = 0; it < 16; ++it) {
            int ch = it * 4 + cg;
            rtile[ch][px] = rb[(size_t)ch * HW_];
        }
        __syncthreads();

        s1 = red1[0][px] + red1[1][px] + red1[2][px] + red1[3][px];
        s2 = red2[0][px] + red2[1][px] + red2[2][px] + red2[3][px];
        float mean = s1 * (1.f / 64.f);
        float var  = (s2 - 64.f * mean * mean) * (1.f / 63.f);
        float inv  = 1.f / sqrtf(var + 1e-5f);
        u16x8 pk[2];
        #pragma unroll
        for (int j = 0; j < 16; ++j) {
            float nv = (v[j] - mean) * inv;
            pk[j >> 3][j & 7] = f2bf(nv);
        }
        size_t bp = (size_t)b * HW_ + p;
        *reinterpret_cast<u16x8*>(&cc[bp * 128 + cg * 16 + 0]) = pk[0];
        *reinterpret_cast<u16x8*>(&cc[bp * 128 + cg * 16 + 8]) = pk[1];

        {
            int wpx = t >> 2, q = t & 3;
            size_t bp2 = (size_t)b * HW_ + p0 + wpx;
            u16x8 o0, o1, h0, h1;
            #pragma unroll
            for (int j = 0; j < 8; ++j) {
                float v0 = rtile[q * 16 + j][wpx];
                float v1 = rtile[q * 16 + 8 + j][wpx];
                o0[j] = f2bf(v0);    o1[j] = f2bf(v1);
                h0[j] = f2hbits(v0); h1[j] = f2hbits(v1);
            }
            *reinterpret_cast<u16x8*>(&cc[bp2 * 128 + 64 + q * 16 + 0]) = o0;
            *reinterpret_cast<u16x8*>(&cc[bp2 * 128 + 64 + q * 16 + 8]) = o1;
            *reinterpret_cast<u16x8*>(&ccH[bp2 * 64 + q * 16 + 0]) = h0;
            *reinterpret_cast<u16x8*>(&ccH[bp2 * 64 + q * 16 + 8]) = h1;
        }
    } else {
        int idx = (blk - 288) * 256 + t;
        if (idx < 9 * 16 * 128) {
            int tap = idx / (16 * 128), oc = (idx / 128) % 16, ic = idx % 128;
            wt1[idx] = f2bf(w1[(oc * 128 + ic) * 9 + tap]);
        }
        if (idx < 9 * 64 * 32) {
            int tap = idx / (64 * 32), oc = (idx / 32) % 64, ic = idx % 32;
            wt2[idx] = (ic < 16) ? f2bf(w2[(oc * 16 + ic) * 9 + tap]) : (unsigned short)0;
        }
        if (idx < 9 * 32 * 64) {
            int tap = idx / (32 * 64), oc = (idx / 64) % 32, ic = idx % 64;
            wtoff[idx] = (oc < 27) ? f2bf(woff[(oc * 64 + ic) * 9 + tap]) : (unsigned short)0;
        }
        if (idx < 9 * 64 * 64) {
            int tap = idx / (64 * 64), oc = (idx / 64) % 64, ic = idx % 64;
            wtg[idx]  = f2bf(wg [(oc * 64 + ic) * 9 + tap]);
            wtbe[idx] = f2bf(wbe[(oc * 64 + ic) * 9 + tap]);
        }
        if (idx < 64 * 576) {
            int oc = idx / 576, r = idx - oc * 576;
            int tap = r >> 6, ic = r & 63;
            wbdH[idx] = f2hbits(wdcn[oc * 576 + ic * 9 + tap]);
        }
    }
}

// ---------------------------------------------------------------------------
// Tap-decomposed MFMA conv 3x3, pad 1, bf16 [p][ICS] input, R-row tiles.
// OMODE 1: bf16 [p][COUT] out.  OMODE 0 + DUAL: final — normalized values
// read from ccn bf16 [p][128] (channels 0..63), out f32 [c][p].
// ---------------------------------------------------------------------------
template <int R, int ICS, int ICP, int COLP, int COUT_PAD, int COUT_REAL,
          bool DUAL, bool RELU, int OMODE>
__global__ __launch_bounds__(256)
void conv_bf(const unsigned short* __restrict__ in,
             const unsigned short* __restrict__ Wt,
             const unsigned short* __restrict__ Wt2,
             const float* __restrict__ bias, const float* __restrict__ bias2,
             const unsigned short* __restrict__ ccn, float* __restrict__ outF,
             unsigned short* __restrict__ outB) {
    constexpr int NOCT = COUT_PAD / 16;
    constexpr int WPO  = 4 / NOCT;
    constexpr int MTP  = R / WPO;
    constexpr int NKS  = ICP / 32;
    constexpr int NCH8 = ICP / 8;
    constexpr int TY   = 96 / R;
    constexpr int PR   = R + 2;

    __shared__ unsigned short patch[PR * 18 * COLP];

    int t   = threadIdx.x;
    int blk = blockIdx.x;                 // B * TY * 6
    int bx  = blk % 6;
    int by  = (blk / 6) % TY;
    int b   = blk / (6 * TY);
    int x0  = bx * 16, y0 = by * R;

    for (int e = t; e < PR * 18 * NCH8; e += 256) {
        int kc  = e % NCH8;
        int col = (e / NCH8) % 18;
        int row = e / (NCH8 * 18);
        int yy = y0 + row - 1, xx = x0 + col - 1;
        bf16x8 v = (bf16x8){0, 0, 0, 0, 0, 0, 0, 0};
        if (kc * 8 < ICS && (unsigned)yy < (unsigned)H_ && (unsigned)xx < (unsigned)W_) {
            v = ld_frag(&in[((size_t)b * HW_ + yy * W_ + xx) * ICS + kc * 8]);
        }
        *reinterpret_cast<bf16x8*>(&patch[(row * 18 + col) * COLP + kc * 8]) = v;
    }
    __syncthreads();

    int wave = t >> 6, lane = t & 63;
    int fr = lane & 15, fq = lane >> 4;
    int oct  = wave / WPO;
    int widx = wave - oct * WPO;
    int mt0  = widx * MTP;

    f32x4 accA[MTP], accB[MTP];
    #pragma unroll
    for (int i = 0; i < MTP; ++i) {
        accA[i] = (f32x4){0.f, 0.f, 0.f, 0.f};
        accB[i] = (f32x4){0.f, 0.f, 0.f, 0.f};
    }

    constexpr int dyv[9] = {0,0,0,1,1,1,2,2,2};
    constexpr int dxv[9] = {0,1,2,0,1,2,0,1,2};

    #pragma unroll
    for (int tap = 0; tap < 9; ++tap) {
        int dy = dyv[tap], dx = dxv[tap];
        #pragma unroll
        for (int ks = 0; ks < NKS; ++ks) {
            const size_t wo = ((size_t)tap * COUT_PAD + oct * 16 + fr) * ICP + ks * 32 + fq * 8;
            bf16x8 wfA = ld_frag(&Wt[wo]);
            bf16x8 wfB;
            if (DUAL) wfB = ld_frag(&Wt2[wo]);
            #pragma unroll
            for (int i = 0; i < MTP; ++i) {
                bf16x8 pf = ld_frag(&patch[((mt0 + i + dy) * 18 + (fr + dx)) * COLP
                                           + ks * 32 + fq * 8]);
                accA[i] = __builtin_amdgcn_mfma_f32_16x16x32_bf16(wfA, pf, accA[i], 0, 0, 0);
                if (DUAL)
                    accB[i] = __builtin_amdgcn_mfma_f32_16x16x32_bf16(wfB, pf, accB[i], 0, 0, 0);
            }
        }
    }

    #pragma unroll
    for (int i = 0; i < MTP; ++i) {
        int py = mt0 + i;
        if (OMODE == 1) {
            size_t p = (size_t)b * HW_ + (size_t)(y0 + py) * W_ + x0 + fr;
            ushort4 sv;
            #pragma unroll
            for (int j = 0; j < 4; ++j) {
                float v = accA[i][j] + bias[oct * 16 + fq * 4 + j];
                if (RELU) v = fmaxf(v, 0.f);
                ((unsigned short*)&sv)[j] = f2bf(v);
            }
            *reinterpret_cast<ushort4*>(&outB[p * COUT_REAL + oct * 16 + fq * 4]) = sv;
        } else {
            size_t pix = (size_t)b * HW_ + (size_t)(y0 + py) * W_ + x0 + fr;
            ushort4 nv4;
            if (DUAL)
                nv4 = *reinterpret_cast<const ushort4*>(&ccn[pix * 128 + oct * 16 + fq * 4]);
            #pragma unroll
            for (int j = 0; j < 4; ++j) {
                int oc = oct * 16 + fq * 4 + j;
                if (oc >= COUT_REAL) continue;
                size_t off = ((size_t)b * COUT_REAL + oc) * HW_
                           + (size_t)(y0 + py) * W_ + x0 + fr;
                float v = accA[i][j] + bias[oc];
                if (DUAL) {
                    float be = accB[i][j] + bias2[oc];
                    float nv = bf2f(((unsigned short*)&nv4)[j]);
                    outF[off] = fmaf(nv, 1.f + v, be);
                } else {
                    outF[off] = RELU ? fmaxf(v, 0.f) : v;
                }
            }
        }
    }
}

// ---------------------------------------------------------------------------
// DCNv2 fused + conv_off in-block (round-10 form). Block = 32 px, grid 576.
// ---------------------------------------------------------------------------
constexpr int SROW = 584;
constexpr int DT   = 32;

__global__ __launch_bounds__(256)
void dcn_kernel(const unsigned short* __restrict__ ccH,
                const unsigned short* __restrict__ condT,
                const unsigned short* __restrict__ wtoff,
                const float* __restrict__ b_off,
                const unsigned short* __restrict__ wbdH,
                const float* __restrict__ b_dcn,
                unsigned short* __restrict__ rrT) {
    __shared__ unsigned short uS[DT * SROW];
    __shared__ float  omL[DT][36];
    __shared__ ushort4 cwLh[DT * 9];
    __shared__ int4    ciL[DT * 9];

    int t = threadIdx.x;
    int bid = blockIdx.x;
    int swz = (bid & 7) * 72 + (bid >> 3);     // bijective, nwg=576
    int b   = swz / (HW_ / DT);
    int p0  = (swz % (HW_ / DT)) * DT;
    int y   = p0 / W_, x0 = p0 - y * W_;

    // ---- phase A: stage cond patch rows y-1..y+1, cols x0-1..x0+32 ----
    for (int e = t; e < 3 * 34 * 8; e += 256) {
        int kc  = e & 7;
        int col = (e >> 3) % 34;
        int row = (e >> 3) / 34;
        int yy = y + row - 1, xx = x0 + col - 1;
        bf16x8 v = (bf16x8){0, 0, 0, 0, 0, 0, 0, 0};
        if ((unsigned)yy < (unsigned)H_ && (unsigned)xx < (unsigned)W_) {
            v = ld_frag(&condT[((size_t)b * HW_ + yy * W_ + xx) * 64 + kc * 8]);
        }
        *reinterpret_cast<bf16x8*>(&uS[(row * 34 + col) * 72 + kc * 8]) = v;
    }
    __syncthreads();

    int wave = t >> 6, lane = t & 63;
    int fr = lane & 15, fq = lane >> 4;

    // ---- phase B: om MFMA ----
    {
        int oct = wave & 1, mt = wave >> 1;
        f32x4 acc = (f32x4){0.f, 0.f, 0.f, 0.f};
        constexpr int dyv[9] = {0,0,0,1,1,1,2,2,2};
        constexpr int dxv[9] = {0,1,2,0,1,2,0,1,2};
        #pragma unroll
        for (int tap = 0; tap < 9; ++tap) {
            int dy = dyv[tap], dx = dxv[tap];
            #pragma unroll
            for (int ks = 0; ks < 2; ++ks) {
                bf16x8 wf = ld_frag(&wtoff[((size_t)tap * 32 + oct * 16 + fr) * 64
                                           + ks * 32 + fq * 8]);
                bf16x8 pf = *reinterpret_cast<const bf16x8*>(
                    &uS[(dy * 34 + mt * 16 + fr + dx) * 72 + ks * 32 + fq * 8]);
                acc = __builtin_amdgcn_mfma_f32_16x16x32_bf16(wf, pf, acc, 0, 0, 0);
            }
        }
        int px = mt * 16 + fr;
        float4 o4;
        #pragma unroll
        for (int j = 0; j < 4; ++j) {
            int oc = oct * 16 + fq * 4 + j;
            ((float*)&o4)[j] = acc[j] + (oc < 27 ? b_off[oc] : 0.f);
        }
        *reinterpret_cast<float4*>(&omL[px][oct * 16 + fq * 4]) = o4;
    }
    __syncthreads();

    // ---- phase 0: corner weights/indices from omL ----
    for (int e = t; e < DT * 9; e += 256) {
        int pp = e / 9, k = e - pp * 9;
        int p  = p0 + pp;
        int yq = p / W_, xq = p - yq * W_;
        float dy = omL[pp][2 * k];
        float dx = omL[pp][2 * k + 1];
        float mk = omL[pp][18 + k];
        mk = 1.f / (1.f + expf(-mk));

        float py = dy + (float)yq + (float)(k / 3 - 1);
        float px = dx + (float)xq + (float)(k % 3 - 1);
        float fy = floorf(py), fx = floorf(px);
        int   y0c = (int)fy,  x0c = (int)fx;
        float wy = py - fy,   wx = px - fx;

        ushort4 cwh;
        int   ci[4];
        #pragma unroll
        for (int i = 0; i < 4; ++i) {
            int yy = y0c + (i >> 1);
            int xx = x0c + (i & 1);
            bool valid = (yy >= 0) && (yy < H_) && (xx >= 0) && (xx < W_);
            int yc = yy < 0 ? 0 : (yy > H_ - 1 ? H_ - 1 : yy);
            int xc = xx < 0 ? 0 : (xx > W_ - 1 ? W_ - 1 : xx);
            ci[i] = yc * W_ + xc;
            float wyi = (i >> 1) ? wy : (1.f - wy);
            float wxi = (i & 1)  ? wx : (1.f - wx);
            ((unsigned short*)&cwh)[i] = f2hbits(valid ? mk * wyi * wxi : 0.f);
        }
        cwLh[e] = cwh;
        ciL[e] = make_int4(ci[0], ci[1], ci[2], ci[3]);
    }
    __syncthreads();

    // ---- phase 1: f16 packed gather (overwrites uS) ----
    {
        const unsigned short* ch = ccH + (size_t)b * HW_ * 64;
        int pp = t >> 3, cg8 = t & 7;
        #pragma unroll
        for (int k = 0; k < 9; ++k) {
            ushort4 cwh = cwLh[pp * 9 + k];
            int4    ci  = ciL[pp * 9 + k];
            f16x8 r0 = *reinterpret_cast<const f16x8*>(&ch[(size_t)ci.x * 64 + cg8 * 8]);
            f16x8 r1 = *reinterpret_cast<const f16x8*>(&ch[(size_t)ci.y * 64 + cg8 * 8]);
            f16x8 r2 = *reinterpret_cast<const f16x8*>(&ch[(size_t)ci.z * 64 + cg8 * 8]);
            f16x8 r3 = *reinterpret_cast<const f16x8*>(&ch[(size_t)ci.w * 64 + cg8 * 8]);
            _Float16 h0 = hfrombits(cwh.x);
            _Float16 h1 = hfrombits(cwh.y);
            _Float16 h2 = hfrombits(cwh.z);
            _Float16 h3 = hfrombits(cwh.w);
            f16x8 s = r0 * h0;
            s += r1 * h1;
            s += r2 * h2;
            s += r3 * h3;
            *reinterpret_cast<f16x8*>(&uS[pp * SROW + k * 64 + cg8 * 8]) = s;
        }
    }
    __syncthreads();

    // ---- phase 2: f16 MFMA matvec ----
    f32x4 acc0 = (f32x4){0.f, 0.f, 0.f, 0.f};
    f32x4 acc1 = (f32x4){0.f, 0.f, 0.f, 0.f};
    for (int ks = 0; ks < 18; ++ks) {
        f16x8 wf  = *reinterpret_cast<const f16x8*>(
            &wbdH[(size_t)(wave * 16 + fr) * 576 + ks * 32 + fq * 8]);
        f16x8 pf0 = *reinterpret_cast<const f16x8*>(
            &uS[(size_t)fr * SROW + ks * 32 + fq * 8]);
        f16x8 pf1 = *reinterpret_cast<const f16x8*>(
            &uS[(size_t)(16 + fr) * SROW + ks * 32 + fq * 8]);
        acc0 = __builtin_amdgcn_mfma_f32_16x16x32_f16(wf, pf0, acc0, 0, 0, 0);
        acc1 = __builtin_amdgcn_mfma_f32_16x16x32_f16(wf, pf1, acc1, 0, 0, 0);
    }

    {
        size_t p = (size_t)b * HW_ + p0 + fr;
        ushort4 sv0, sv1;
        #pragma unroll
        for (int j = 0; j < 4; ++j) {
            float bo = b_dcn[wave * 16 + fq * 4 + j];
            ((unsigned short*)&sv0)[j] = f2bf(acc0[j] + bo);
            ((unsigned short*)&sv1)[j] = f2bf(acc1[j] + bo);
        }
        *reinterpret_cast<ushort4*>(&rrT[p * 64 + wave * 16 + fq * 4]) = sv0;
        *reinterpret_cast<ushort4*>(&rrT[(p + 16) * 64 + wave * 16 + fq * 4]) = sv1;
    }
}

} // namespace

// ---------------------------------------------------------------------------
extern "C" void kernel_launch(void* const* d_in, const int* in_sizes, int n_in,
                              void* d_out, int out_size, void* d_ws, size_t ws_size,
                              hipStream_t stream) {
    (void)in_sizes; (void)n_in; (void)out_size; (void)ws_size;

    const float* x     = (const float*)d_in[0];
    const float* ref   = (const float*)d_in[1];
    const float* w1    = (const float*)d_in[2];
    const float* b1    = (const float*)d_in[3];
    const float* w2    = (const float*)d_in[4];
    const float* b2    = (const float*)d_in[5];
    const float* w_off = (const float*)d_in[6];
    const float* b_off = (const float*)d_in[7];
    const float* w_dcn = (const float*)d_in[8];
    const float* b_dcn = (const float*)d_in[9];
    const float* w_g   = (const float*)d_in[10];
    const float* b_g   = (const float*)d_in[11];
    const float* w_be  = (const float*)d_in[12];
    const float* b_be  = (const float*)d_in[13];

    float* out = (float*)d_out;

    unsigned short* cc    = (unsigned short*)d_ws;           // [b][p][128] bf16
    unsigned short* ccH   = cc    + 2359296;                 // [b][p][64]  f16
    unsigned short* hmidT = ccH   + 1179648;                 // [b][p][16]  bf16
    unsigned short* condT = hmidT + 294912;                  // [b][p][64]  bf16
    unsigned short* rrT   = condT + 1179648;                 // [b][p][64]  bf16
    unsigned short* wt1   = rrT   + 1179648;
    unsigned short* wt2   = wt1   + 18432;
    unsigned short* wtoff = wt2   + 18432;
    unsigned short* wtg   = wtoff + 18432;
    unsigned short* wtbe  = wtg   + 36864;
    unsigned short* wbdH  = wtbe  + 36864;

    prologue<<<432, 256, 0, stream>>>(x, ref, w1, w2, w_off, w_g, w_be, w_dcn,
                                      cc, ccH, wt1, wt2, wtoff, wtg, wtbe, wbdH);

    // conv1: cc[p][128] -> hmidT[p][16], ReLU. R=4, grid 288.
    conv_bf<4, 128, 128, 136, 16, 16, false, true, 1>
        <<<288, 256, 0, stream>>>(cc, wt1, nullptr, b1, nullptr, nullptr, nullptr, hmidT);

    // conv2: hmidT[p][16] -> condT[p][64], ReLU. R=4, grid 288.
    conv_bf<4, 16, 32, 40, 64, 64, false, true, 1>
        <<<288, 256, 0, stream>>>(hmidT, wt2, nullptr, b2, nullptr, nullptr, nullptr, condT);

    // dcn (+conv_off): condT/ccH -> rrT. grid 576.
    dcn_kernel<<<576, 256, 0, stream>>>(ccH, condT, wtoff, b_off, wbdH, b_dcn, rrT);

    // final: rrT[p][64] -> out f32 [64][p]; normalized read from cc bf16.
    conv_bf<2, 64, 64, 72, 64, 64, true, false, 0>
        <<<576, 256, 0, stream>>>(rrT, wtg, wtbe, b_g, b_be, cc, out, nullptr);
}